// Round 13
// baseline (1259.591 us; speedup 1.0000x reference)
//
#include <hip/hip_runtime.h>
#include <hip/hip_bf16.h>
#include <math.h>
#include <stdint.h>

typedef __attribute__((ext_vector_type(4))) float f32x4;
typedef __attribute__((ext_vector_type(8))) short s16x8;
typedef __attribute__((ext_vector_type(4))) short s16x4;

struct sh2 { short hi, lo; };

// fp32 -> bf16 hi/lo split. hi = bf16(x) (RNE), lo = bf16(x - hi).
__device__ __forceinline__ sh2 splitf(float x)
{
    __hip_bfloat16 h = __float2bfloat16(x);
    float hf = __bfloat162float(h);
    __hip_bfloat16 l = __float2bfloat16(x - hf);
    sh2 r;
    r.hi = __builtin_bit_cast(short, h);
    r.lo = __builtin_bit_cast(short, l);
    return r;
}

__device__ __forceinline__ void split8(const float4& a, const float4& b,
                                       s16x8& h, s16x8& l)
{
    sh2 p;
    p = splitf(a.x); h[0] = p.hi; l[0] = p.lo;
    p = splitf(a.y); h[1] = p.hi; l[1] = p.lo;
    p = splitf(a.z); h[2] = p.hi; l[2] = p.lo;
    p = splitf(a.w); h[3] = p.hi; l[3] = p.lo;
    p = splitf(b.x); h[4] = p.hi; l[4] = p.lo;
    p = splitf(b.y); h[5] = p.hi; l[5] = p.lo;
    p = splitf(b.z); h[6] = p.hi; l[6] = p.lo;
    p = splitf(b.w); h[7] = p.hi; l[7] = p.lo;
}

// async global->LDS 16B copy (wave-uniform LDS base; lane writes base+lane*16)
typedef const __attribute__((address_space(1))) void gvoid_t;
typedef __attribute__((address_space(3))) void lvoid_t;
__device__ __forceinline__ void gld_lds16(const void* g, void* l)
{
    __builtin_amdgcn_global_load_lds((gvoid_t*)(uintptr_t)g,
                                     (lvoid_t*)(uintptr_t)l, 16, 0, 0);
}

// ============================================================================
// split-bf16 MFMA GEMM (128x128 tile): C = alpha*(A @ B^T) [+bias] [ReLU]
// A pre-split. BF=0: B fp32 (N x K), split inline. BF=1: B pre-split.
// EPI=0 fp32 C [RELU]; EPI=1 split C; EPI=2 in-proj. SK>1: raw fp32 partials.
// 2-phase dbuf; chunk-XOR bank swizzle on SOURCE; XCD block swizzle.
// ============================================================================
template<int BF, int EPI, bool RELU>
__global__ __launch_bounds__(256, 2) void mfma_gemm(
    const short* __restrict__ Ahi, const short* __restrict__ Alo, int lda, long sA,
    const float* __restrict__ Bf, const short* __restrict__ Bhi,
    const short* __restrict__ Blo, int ldb, long sB,
    float* __restrict__ Cf, short* __restrict__ Chi, short* __restrict__ Clo,
    short* __restrict__ Thi, short* __restrict__ Tlo, int ldc, int ldT, long sC,
    int K, int SK, float alpha, const float* __restrict__ bias, int mskip)
{
    __shared__ short SH[2][16384];
    const int zf = blockIdx.z;
    const int sk = (SK > 1) ? (zf % SK) : 0;
    const int bz = (SK > 1) ? (zf / SK) : zf;
    const int Kc = K / SK;
    const int kb = sk * Kc;
    Ahi += (long)bz * sA; Alo += (long)bz * sA;
    if (BF == 0) Bf += (long)bz * sB; else { Bhi += (long)bz * sB; Blo += (long)bz * sB; }
    const long cofs = (long)((SK > 1) ? zf : bz) * sC;

    const int GX = gridDim.x, GY = gridDim.y;
    const int nwg = GX * GY;
    const int bid = blockIdx.x + GX * blockIdx.y;
    const int q8 = nwg >> 3, r8 = nwg & 7;
    const int xcd = bid & 7, sl = bid >> 3;
    const int t = (xcd < r8) ? (xcd * (q8 + 1) + sl)
                             : (r8 * (q8 + 1) + (xcd - r8) * q8 + sl);
    const int m0 = (t % GY) * 128, n0 = (t / GY) * 128;

    if (EPI == 2 && n0 < 4096 && m0 >= mskip) return;

    const int tid = threadIdx.x;
    const int lane = tid & 63, wave = tid >> 6;
    const int wr = (wave >> 1) * 64, wc = (wave & 1) * 64;
    const int lrow = lane & 15, lk = lane >> 4;
    const int cswz8 = (lk ^ ((lrow >> 1) & 3)) << 3;

    const int rA0 = wave * 16 + (lane >> 2);
    const int rA1 = rA0 + 64;
    const int sc0 = ((lane & 3) ^ ((rA0 >> 1) & 3)) * 8;
    const int sc1 = ((lane & 3) ^ ((rA1 >> 1) & 3)) * 8;
    const long gA0 = (long)(m0 + rA0) * lda + sc0;
    const long gA1 = (long)(m0 + rA1) * lda + sc1;
    long gB0 = 0, gB1 = 0;
    if (BF == 1) {
        gB0 = (long)(n0 + rA0) * ldb + sc0;
        gB1 = (long)(n0 + rA1) * ldb + sc1;
    }
    const int lw0 = wave * 512, lw1 = wave * 512 + 2048;

    const int brow = tid & 127;
    const int bkc0 = (tid >> 7) * 8;
    const int bkc1 = bkc0 + 16;
    const int bw0 = brow * 32 + (((bkc0 >> 3) ^ ((brow >> 1) & 3)) << 3);
    const int bw1 = brow * 32 + (((bkc1 >> 3) ^ ((brow >> 1) & 3)) << 3);
    const float* bpr = (BF == 0) ? Bf + (long)(n0 + brow) * ldb : nullptr;

    f32x4 acc[4][4];
#pragma unroll
    for (int i = 0; i < 4; i++)
#pragma unroll
        for (int j = 0; j < 4; j++) acc[i][j] = (f32x4){0.f, 0.f, 0.f, 0.f};

    float4 rb0a, rb0b, rb1a, rb1b;

    {
        short* S = &SH[0][0];
        gld_lds16(Ahi + gA0 + kb, S + lw0);
        gld_lds16(Ahi + gA1 + kb, S + lw1);
        gld_lds16(Alo + gA0 + kb, S + 4096 + lw0);
        gld_lds16(Alo + gA1 + kb, S + 4096 + lw1);
        if constexpr (BF == 1) {
            gld_lds16(Bhi + gB0 + kb, S + 8192 + lw0);
            gld_lds16(Bhi + gB1 + kb, S + 8192 + lw1);
            gld_lds16(Blo + gB0 + kb, S + 12288 + lw0);
            gld_lds16(Blo + gB1 + kb, S + 12288 + lw1);
        } else {
            rb0a = *(const float4*)(bpr + kb + bkc0);
            rb0b = *(const float4*)(bpr + kb + bkc0 + 4);
            rb1a = *(const float4*)(bpr + kb + bkc1);
            rb1b = *(const float4*)(bpr + kb + bkc1 + 4);
            s16x8 h, l;
            split8(rb0a, rb0b, h, l);
            *(s16x8*)&S[8192 + bw0] = h;
            *(s16x8*)&S[12288 + bw0] = l;
            split8(rb1a, rb1b, h, l);
            *(s16x8*)&S[8192 + bw1] = h;
            *(s16x8*)&S[12288 + bw1] = l;
        }
    }
    __syncthreads();

    int cur = 0;
    const int kend = kb + Kc;
    for (int k0 = kb; k0 < kend; k0 += 32) {
        const int kn = k0 + 32;
        const bool nx = (kn < kend);
        short* SN = &SH[cur ^ 1][0];
        if (nx) {
            gld_lds16(Ahi + gA0 + kn, SN + lw0);
            gld_lds16(Ahi + gA1 + kn, SN + lw1);
            gld_lds16(Alo + gA0 + kn, SN + 4096 + lw0);
            gld_lds16(Alo + gA1 + kn, SN + 4096 + lw1);
            if constexpr (BF == 1) {
                gld_lds16(Bhi + gB0 + kn, SN + 8192 + lw0);
                gld_lds16(Bhi + gB1 + kn, SN + 8192 + lw1);
                gld_lds16(Blo + gB0 + kn, SN + 12288 + lw0);
                gld_lds16(Blo + gB1 + kn, SN + 12288 + lw1);
            } else {
                rb0a = *(const float4*)(bpr + kn + bkc0);
                rb0b = *(const float4*)(bpr + kn + bkc0 + 4);
                rb1a = *(const float4*)(bpr + kn + bkc1);
                rb1b = *(const float4*)(bpr + kn + bkc1 + 4);
            }
        }
        const short* S = &SH[cur][0];
        s16x8 ah[4], al[4], bh[4], bl[4];
#pragma unroll
        for (int m = 0; m < 4; m++) {
            const int idx = (wr + m * 16 + lrow) * 32 + cswz8;
            ah[m] = *(const s16x8*)&S[idx];
            al[m] = *(const s16x8*)&S[4096 + idx];
        }
#pragma unroll
        for (int n = 0; n < 4; n++) {
            const int idx = (wc + n * 16 + lrow) * 32 + cswz8;
            bh[n] = *(const s16x8*)&S[8192 + idx];
            bl[n] = *(const s16x8*)&S[12288 + idx];
        }
#pragma unroll
        for (int n = 0; n < 4; n++)
#pragma unroll
            for (int m = 0; m < 4; m++)
                acc[m][n] = __builtin_amdgcn_mfma_f32_16x16x32_bf16(ah[m], bh[n], acc[m][n], 0, 0, 0);
#pragma unroll
        for (int n = 0; n < 4; n++)
#pragma unroll
            for (int m = 0; m < 4; m++)
                acc[m][n] = __builtin_amdgcn_mfma_f32_16x16x32_bf16(ah[m], bl[n], acc[m][n], 0, 0, 0);
#pragma unroll
        for (int n = 0; n < 4; n++)
#pragma unroll
            for (int m = 0; m < 4; m++)
                acc[m][n] = __builtin_amdgcn_mfma_f32_16x16x32_bf16(al[m], bh[n], acc[m][n], 0, 0, 0);
        if (BF == 0 && nx) {
            s16x8 h, l;
            split8(rb0a, rb0b, h, l);
            *(s16x8*)&SN[8192 + bw0] = h;
            *(s16x8*)&SN[12288 + bw0] = l;
            split8(rb1a, rb1b, h, l);
            *(s16x8*)&SN[8192 + bw1] = h;
            *(s16x8*)&SN[12288 + bw1] = l;
        }
        __syncthreads();
        cur ^= 1;
    }
#pragma unroll
    for (int n = 0; n < 4; n++) {
        const int col = n0 + wc + n * 16 + lrow;
        const float bv = (SK == 1 && bias) ? bias[col] : 0.f;
#pragma unroll
        for (int m = 0; m < 4; m++) {
            const int row = m0 + wr + m * 16 + lk * 4;
            if (SK > 1) {
#pragma unroll
                for (int r = 0; r < 4; r++)
                    Cf[cofs + (long)(row + r) * ldc + col] = acc[m][n][r] * alpha;
            } else if constexpr (EPI == 0) {
#pragma unroll
                for (int r = 0; r < 4; r++) {
                    float v = acc[m][n][r] * alpha + bv;
                    if (RELU) v = fmaxf(v, 0.f);
                    Cf[cofs + (long)(row + r) * ldc + col] = v;
                }
            } else if constexpr (EPI == 1) {
#pragma unroll
                for (int r = 0; r < 4; r++) {
                    float v = acc[m][n][r] * alpha + bv;
                    sh2 p = splitf(v);
                    Chi[cofs + (long)(row + r) * ldc + col] = p.hi;
                    Clo[cofs + (long)(row + r) * ldc + col] = p.lo;
                }
            } else {
                if (n0 < 8192) {
#pragma unroll
                    for (int r = 0; r < 4; r++) {
                        float v = acc[m][n][r] + bv;
                        sh2 p = splitf(v);
                        Chi[(long)(row + r) * ldc + col] = p.hi;
                        Clo[(long)(row + r) * ldc + col] = p.lo;
                    }
                } else {
                    s16x4 h4, l4;
#pragma unroll
                    for (int r = 0; r < 4; r++) {
                        float v = acc[m][n][r] + bv;
                        sh2 p = splitf(v);
                        h4[r] = p.hi; l4[r] = p.lo;
                    }
                    const long tof = (long)(col - 8192) * ldT + row;
                    *(s16x4*)&Thi[tof] = h4;
                    *(s16x4*)&Tlo[tof] = l4;
                }
            }
        }
    }
}

// ============================================================================
// 256x256-tile split-bf16 GEMM, BF=0, EPI=2 (in-proj), 8 waves, 128 KB LDS.
// mskip: dead-block exit for q-cols x te-rows.
// ============================================================================
__global__ __launch_bounds__(512, 2) void mfma_gemm256(
    const short* __restrict__ Ahi, const short* __restrict__ Alo, int lda,
    const float* __restrict__ Bf, int ldb,
    short* __restrict__ Chi, short* __restrict__ Clo,
    short* __restrict__ Thi, short* __restrict__ Tlo, int ldc, int ldT,
    int K, int Mreal, const float* __restrict__ bias, int mskip)
{
    __shared__ short SH[2][32768];

    const int GX = gridDim.x, GY = gridDim.y;
    const int nwg = GX * GY;
    const int bid = blockIdx.x + GX * blockIdx.y;
    const int q8 = nwg >> 3, r8 = nwg & 7;
    const int xcd = bid & 7, sl = bid >> 3;
    const int t = (xcd < r8) ? (xcd * (q8 + 1) + sl)
                             : (r8 * (q8 + 1) + (xcd - r8) * q8 + sl);
    const int m0 = (t % GY) * 256, n0 = (t / GY) * 256;

    if (n0 < 4096 && m0 >= mskip) return;

    const int tid = threadIdx.x;
    const int lane = tid & 63, wave = tid >> 6;
    const int wr = (wave >> 1) * 64, wc = (wave & 1) * 128;
    const int lrow = lane & 15, lk = lane >> 4;
    const int cswz8 = (lk ^ ((lrow >> 1) & 3)) << 3;

    const int rA0 = wave * 32 + (lane >> 2);
    const int rA1 = rA0 + 16;
    const int sc0 = ((lane & 3) ^ ((rA0 >> 1) & 3)) * 8;
    const int sc1 = ((lane & 3) ^ ((rA1 >> 1) & 3)) * 8;
    const long gA0 = (long)(m0 + rA0) * lda + sc0;
    const long gA1 = (long)(m0 + rA1) * lda + sc1;
    const int lw0 = wave * 1024, lw1 = wave * 1024 + 512;

    const int brow = tid & 255;
    const int bk = (tid >> 8) * 16;
    const int bw0 = brow * 32 + ((((bk >> 3) + 0) ^ ((brow >> 1) & 3)) << 3);
    const int bw1 = brow * 32 + ((((bk >> 3) + 1) ^ ((brow >> 1) & 3)) << 3);
    const float* bpr = Bf + (long)(n0 + brow) * ldb + bk;

    f32x4 acc[4][8];
#pragma unroll
    for (int i = 0; i < 4; i++)
#pragma unroll
        for (int j = 0; j < 8; j++) acc[i][j] = (f32x4){0.f, 0.f, 0.f, 0.f};

    float4 rb0, rb1, rb2, rb3;

    {
        short* S = &SH[0][0];
        gld_lds16(Ahi + gA0, S + lw0);
        gld_lds16(Ahi + gA1, S + lw1);
        gld_lds16(Alo + gA0, S + 8192 + lw0);
        gld_lds16(Alo + gA1, S + 8192 + lw1);
        rb0 = *(const float4*)(bpr + 0);
        rb1 = *(const float4*)(bpr + 4);
        rb2 = *(const float4*)(bpr + 8);
        rb3 = *(const float4*)(bpr + 12);
        s16x8 h, l;
        split8(rb0, rb1, h, l);
        *(s16x8*)&S[16384 + bw0] = h;
        *(s16x8*)&S[24576 + bw0] = l;
        split8(rb2, rb3, h, l);
        *(s16x8*)&S[16384 + bw1] = h;
        *(s16x8*)&S[24576 + bw1] = l;
    }
    __syncthreads();

    int cur = 0;
    for (int k0 = 0; k0 < K; k0 += 32) {
        const int kn = k0 + 32;
        const bool nx = (kn < K);
        short* SN = &SH[cur ^ 1][0];
        if (nx) {
            gld_lds16(Ahi + gA0 + kn, SN + lw0);
            gld_lds16(Ahi + gA1 + kn, SN + lw1);
            gld_lds16(Alo + gA0 + kn, SN + 8192 + lw0);
            gld_lds16(Alo + gA1 + kn, SN + 8192 + lw1);
            rb0 = *(const float4*)(bpr + kn + 0);
            rb1 = *(const float4*)(bpr + kn + 4);
            rb2 = *(const float4*)(bpr + kn + 8);
            rb3 = *(const float4*)(bpr + kn + 12);
        }
        const short* S = &SH[cur][0];
        s16x8 ah[4], al[4];
#pragma unroll
        for (int m = 0; m < 4; m++) {
            const int idx = (wr + m * 16 + lrow) * 32 + cswz8;
            ah[m] = *(const s16x8*)&S[idx];
            al[m] = *(const s16x8*)&S[8192 + idx];
        }
#pragma unroll
        for (int np = 0; np < 4; np++) {
            s16x8 bh[2], bl[2];
#pragma unroll
            for (int j = 0; j < 2; j++) {
                const int idx = (wc + (np * 2 + j) * 16 + lrow) * 32 + cswz8;
                bh[j] = *(const s16x8*)&S[16384 + idx];
                bl[j] = *(const s16x8*)&S[24576 + idx];
            }
#pragma unroll
            for (int j = 0; j < 2; j++)
#pragma unroll
                for (int m = 0; m < 4; m++)
                    acc[m][np * 2 + j] = __builtin_amdgcn_mfma_f32_16x16x32_bf16(ah[m], bh[j], acc[m][np * 2 + j], 0, 0, 0);
#pragma unroll
            for (int j = 0; j < 2; j++)
#pragma unroll
                for (int m = 0; m < 4; m++)
                    acc[m][np * 2 + j] = __builtin_amdgcn_mfma_f32_16x16x32_bf16(ah[m], bl[j], acc[m][np * 2 + j], 0, 0, 0);
#pragma unroll
            for (int j = 0; j < 2; j++)
#pragma unroll
                for (int m = 0; m < 4; m++)
                    acc[m][np * 2 + j] = __builtin_amdgcn_mfma_f32_16x16x32_bf16(al[m], bh[j], acc[m][np * 2 + j], 0, 0, 0);
        }
        if (nx) {
            s16x8 h, l;
            split8(rb0, rb1, h, l);
            *(s16x8*)&SN[16384 + bw0] = h;
            *(s16x8*)&SN[24576 + bw0] = l;
            split8(rb2, rb3, h, l);
            *(s16x8*)&SN[16384 + bw1] = h;
            *(s16x8*)&SN[24576 + bw1] = l;
        }
        __syncthreads();
        cur ^= 1;
    }
#pragma unroll
    for (int n = 0; n < 8; n++) {
        const int col = n0 + wc + n * 16 + lrow;
        const float bv = bias[col];
#pragma unroll
        for (int m = 0; m < 4; m++) {
            const int row = m0 + wr + m * 16 + lk * 4;
            if (row < Mreal) {
                if (n0 < 8192) {
#pragma unroll
                    for (int r = 0; r < 4; r++) {
                        float v = acc[m][n][r] + bv;
                        sh2 p = splitf(v);
                        Chi[(long)(row + r) * ldc + col] = p.hi;
                        Clo[(long)(row + r) * ldc + col] = p.lo;
                    }
                } else {
                    s16x4 h4, l4;
#pragma unroll
                    for (int r = 0; r < 4; r++) {
                        float v = acc[m][n][r] + bv;
                        sh2 p = splitf(v);
                        h4[r] = p.hi; l4[r] = p.lo;
                    }
                    const long tof = (long)(col - 8192) * ldT + row;
                    *(s16x4*)&Thi[tof] = h4;
                    *(s16x4*)&Tlo[tof] = l4;
                }
            }
        }
    }
}

// ============================================================================
// 256x256-tile split-bf16 GEMM with split-K, BF=0 (fp32 B), raw fp32 partials.
// ============================================================================
__global__ __launch_bounds__(512, 2) void mfma_gemm256sk(
    const short* __restrict__ Ahi, const short* __restrict__ Alo, int lda,
    const float* __restrict__ Bf, int ldb,
    float* __restrict__ P, long zstride, int ldp,
    int K, int SK)
{
    __shared__ short SH[2][32768];

    const int sk = blockIdx.z;
    const int Kc = K / SK;
    const int kb = sk * Kc;

    const int GX = gridDim.x, GY = gridDim.y;
    const int nwg = GX * GY;
    const int bid = blockIdx.x + GX * blockIdx.y;
    const int q8 = nwg >> 3, r8 = nwg & 7;
    const int xcd = bid & 7, sl = bid >> 3;
    const int t = (xcd < r8) ? (xcd * (q8 + 1) + sl)
                             : (r8 * (q8 + 1) + (xcd - r8) * q8 + sl);
    const int m0 = (t % GY) * 256, n0 = (t / GY) * 256;

    const int tid = threadIdx.x;
    const int lane = tid & 63, wave = tid >> 6;
    const int wr = (wave >> 1) * 64, wc = (wave & 1) * 128;
    const int lrow = lane & 15, lk = lane >> 4;
    const int cswz8 = (lk ^ ((lrow >> 1) & 3)) << 3;

    const int rA0 = wave * 32 + (lane >> 2);
    const int rA1 = rA0 + 16;
    const int sc0 = ((lane & 3) ^ ((rA0 >> 1) & 3)) * 8;
    const int sc1 = ((lane & 3) ^ ((rA1 >> 1) & 3)) * 8;
    const long gA0 = (long)(m0 + rA0) * lda + sc0;
    const long gA1 = (long)(m0 + rA1) * lda + sc1;
    const int lw0 = wave * 1024, lw1 = wave * 1024 + 512;

    const int brow = tid & 255;
    const int bk = (tid >> 8) * 16;
    const int bw0 = brow * 32 + ((((bk >> 3) + 0) ^ ((brow >> 1) & 3)) << 3);
    const int bw1 = brow * 32 + ((((bk >> 3) + 1) ^ ((brow >> 1) & 3)) << 3);
    const float* bpr = Bf + (long)(n0 + brow) * ldb + bk;

    f32x4 acc[4][8];
#pragma unroll
    for (int i = 0; i < 4; i++)
#pragma unroll
        for (int j = 0; j < 8; j++) acc[i][j] = (f32x4){0.f, 0.f, 0.f, 0.f};

    float4 rb0, rb1, rb2, rb3;

    {
        short* S = &SH[0][0];
        gld_lds16(Ahi + gA0 + kb, S + lw0);
        gld_lds16(Ahi + gA1 + kb, S + lw1);
        gld_lds16(Alo + gA0 + kb, S + 8192 + lw0);
        gld_lds16(Alo + gA1 + kb, S + 8192 + lw1);
        rb0 = *(const float4*)(bpr + kb + 0);
        rb1 = *(const float4*)(bpr + kb + 4);
        rb2 = *(const float4*)(bpr + kb + 8);
        rb3 = *(const float4*)(bpr + kb + 12);
        s16x8 h, l;
        split8(rb0, rb1, h, l);
        *(s16x8*)&S[16384 + bw0] = h;
        *(s16x8*)&S[24576 + bw0] = l;
        split8(rb2, rb3, h, l);
        *(s16x8*)&S[16384 + bw1] = h;
        *(s16x8*)&S[24576 + bw1] = l;
    }
    __syncthreads();

    int cur = 0;
    const int kend = kb + Kc;
    for (int k0 = kb; k0 < kend; k0 += 32) {
        const int kn = k0 + 32;
        const bool nx = (kn < kend);
        short* SN = &SH[cur ^ 1][0];
        if (nx) {
            gld_lds16(Ahi + gA0 + kn, SN + lw0);
            gld_lds16(Ahi + gA1 + kn, SN + lw1);
            gld_lds16(Alo + gA0 + kn, SN + 8192 + lw0);
            gld_lds16(Alo + gA1 + kn, SN + 8192 + lw1);
            rb0 = *(const float4*)(bpr + kn + 0);
            rb1 = *(const float4*)(bpr + kn + 4);
            rb2 = *(const float4*)(bpr + kn + 8);
            rb3 = *(const float4*)(bpr + kn + 12);
        }
        const short* S = &SH[cur][0];
        s16x8 ah[4], al[4];
#pragma unroll
        for (int m = 0; m < 4; m++) {
            const int idx = (wr + m * 16 + lrow) * 32 + cswz8;
            ah[m] = *(const s16x8*)&S[idx];
            al[m] = *(const s16x8*)&S[8192 + idx];
        }
#pragma unroll
        for (int np = 0; np < 4; np++) {
            s16x8 bh[2], bl[2];
#pragma unroll
            for (int j = 0; j < 2; j++) {
                const int idx = (wc + (np * 2 + j) * 16 + lrow) * 32 + cswz8;
                bh[j] = *(const s16x8*)&S[16384 + idx];
                bl[j] = *(const s16x8*)&S[24576 + idx];
            }
#pragma unroll
            for (int j = 0; j < 2; j++)
#pragma unroll
                for (int m = 0; m < 4; m++)
                    acc[m][np * 2 + j] = __builtin_amdgcn_mfma_f32_16x16x32_bf16(ah[m], bh[j], acc[m][np * 2 + j], 0, 0, 0);
#pragma unroll
            for (int j = 0; j < 2; j++)
#pragma unroll
                for (int m = 0; m < 4; m++)
                    acc[m][np * 2 + j] = __builtin_amdgcn_mfma_f32_16x16x32_bf16(ah[m], bl[j], acc[m][np * 2 + j], 0, 0, 0);
#pragma unroll
            for (int j = 0; j < 2; j++)
#pragma unroll
                for (int m = 0; m < 4; m++)
                    acc[m][np * 2 + j] = __builtin_amdgcn_mfma_f32_16x16x32_bf16(al[m], bh[j], acc[m][np * 2 + j], 0, 0, 0);
        }
        if (nx) {
            s16x8 h, l;
            split8(rb0, rb1, h, l);
            *(s16x8*)&SN[16384 + bw0] = h;
            *(s16x8*)&SN[24576 + bw0] = l;
            split8(rb2, rb3, h, l);
            *(s16x8*)&SN[16384 + bw1] = h;
            *(s16x8*)&SN[24576 + bw1] = l;
        }
        __syncthreads();
        cur ^= 1;
    }
    const long zofs = (long)sk * zstride;
#pragma unroll
    for (int n = 0; n < 8; n++) {
        const int col = n0 + wc + n * 16 + lrow;
#pragma unroll
        for (int m = 0; m < 4; m++) {
            const int row = m0 + wr + m * 16 + lk * 4;
#pragma unroll
            for (int r = 0; r < 4; r++)
                P[zofs + (long)(row + r) * ldp + col] = acc[m][n][r];
        }
    }
}

// ============================================================================
// split-K reducer: sums SK partials in fixed order + epilogue
// ============================================================================
template<int EPI, bool RELU>
__global__ __launch_bounds__(256) void reduce_k(
    const float* __restrict__ P, long zstride, int SK, int total,
    int Ninner, int ldc, int colstep,
    float* __restrict__ Cf, short* __restrict__ Chi, short* __restrict__ Clo,
    const float* __restrict__ bias)
{
    const int bz = blockIdx.y;
    const long pbase = (long)bz * SK * zstride;
    const int e = (blockIdx.x * 256 + threadIdx.x) * 4;
    if (e >= total) return;
    const float* p = P + pbase + e;
    float4 s = *(const float4*)p;
    for (int k = 1; k < SK; k++) {
        float4 tv = *(const float4*)(p + (long)k * zstride);
        s.x += tv.x; s.y += tv.y; s.z += tv.z; s.w += tv.w;
    }
    const int r = e / Ninner, c = e % Ninner;
    const int col0 = colstep * bz + c;
    const long ob = (long)r * ldc + col0;
    float v[4] = {s.x, s.y, s.z, s.w};
#pragma unroll
    for (int j = 0; j < 4; j++) {
        float x = v[j] + (bias ? bias[col0 + j] : 0.f);
        if (RELU) x = fmaxf(x, 0.f);
        if constexpr (EPI == 0) {
            Cf[ob + j] = x;
        } else {
            sh2 pp = splitf(x);
            Chi[ob + j] = pp.hi;
            Clo[ob + j] = pp.lo;
        }
    }
}

// split comb rows: r < Mvf -> vf[map? map[r]:r]; else te[r - Mvf]
__global__ __launch_bounds__(256) void split_comb(
    const float* __restrict__ vf, const float* __restrict__ te,
    const int* __restrict__ map, int Mvf,
    short* __restrict__ dhi, short* __restrict__ dlo)
{
    const int r = blockIdx.x;
    const float* srow;
    if (r < Mvf) srow = vf + (long)(map ? map[r] : r) * 4096;
    else         srow = te + (long)(r - Mvf) * 4096;
    const float4* s = (const float4*)srow;
    const long db = (long)r * 4096;
    for (int i = threadIdx.x; i < 1024; i += 256) {
        float4 f = s[i];
        s16x4 h, l;
        sh2 p;
        p = splitf(f.x); h[0] = p.hi; l[0] = p.lo;
        p = splitf(f.y); h[1] = p.hi; l[1] = p.lo;
        p = splitf(f.z); h[2] = p.hi; l[2] = p.lo;
        p = splitf(f.w); h[3] = p.hi; l[3] = p.lo;
        *(s16x4*)&dhi[db + i * 4] = h;
        *(s16x4*)&dlo[db + i * 4] = l;
    }
}

// row softmax (jax.nn.softmax) -> split probs
__global__ __launch_bounds__(256) void softmax_split(
    const float* __restrict__ x, short* __restrict__ phi, short* __restrict__ plo,
    int cols)
{
    const long rb = (long)blockIdx.x * cols;
    const float4* xr = (const float4*)(x + rb);
    const int t = threadIdx.x;
    const int n4 = cols >> 2;
    __shared__ float red[256];
    float mx = -INFINITY;
    for (int i = t; i < n4; i += 256) {
        float4 f = xr[i];
        mx = fmaxf(fmaxf(mx, fmaxf(f.x, f.y)), fmaxf(f.z, f.w));
    }
    red[t] = mx; __syncthreads();
    for (int off = 128; off; off >>= 1) { if (t < off) red[t] = fmaxf(red[t], red[t + off]); __syncthreads(); }
    mx = red[0]; __syncthreads();
    float4 ebuf[2];
    float s = 0.f;
    int nb = 0;
    for (int i = t; i < n4; i += 256) {
        float4 f = xr[i];
        f.x = expf(f.x - mx); f.y = expf(f.y - mx); f.z = expf(f.z - mx); f.w = expf(f.w - mx);
        ebuf[nb++] = f;
        s += f.x + f.y + f.z + f.w;
    }
    red[t] = s; __syncthreads();
    for (int off = 128; off; off >>= 1) { if (t < off) red[t] += red[t + off]; __syncthreads(); }
    s = red[0];
    nb = 0;
    for (int i = t; i < n4; i += 256) {
        float4 f = ebuf[nb++];
        f.x /= s; f.y /= s; f.z /= s; f.w /= s;
        s16x4 h, l;
        sh2 p;
        p = splitf(f.x); h[0] = p.hi; l[0] = p.lo;
        p = splitf(f.y); h[1] = p.hi; l[1] = p.lo;
        p = splitf(f.z); h[2] = p.hi; l[2] = p.lo;
        p = splitf(f.w); h[3] = p.hi; l[3] = p.lo;
        *(s16x4*)&phi[rb + i * 4] = h;
        *(s16x4*)&plo[rb + i * 4] = l;
    }
}

// logits[r] = H[r,:2048] . w2 + b2
__global__ __launch_bounds__(256) void gemv_kernel(
    const float* __restrict__ H, const float* __restrict__ w2,
    const float* __restrict__ b2, float* __restrict__ logits)
{
    const int r = blockIdx.x, t = threadIdx.x;
    const float* row = H + (long)r * 2048;
    float s = 0.f;
    for (int c = t; c < 2048; c += 256) s += row[c] * w2[c];
    __shared__ float red[256];
    red[t] = s; __syncthreads();
    for (int off = 128; off; off >>= 1) { if (t < off) red[t] += red[t + off]; __syncthreads(); }
    if (!t) logits[r] = red[0] + b2[0];
}

// exact lax.top_k: bitonic full sort, desc by val, ties idx asc. blockDim==n.
__global__ void topk_kernel(const float* __restrict__ vals, int n, int k, int* __restrict__ out)
{
    __shared__ float sv[1024];
    __shared__ int   si[1024];
    const int t = threadIdx.x;
    sv[t] = vals[t]; si[t] = t;
    for (int size = 2; size <= n; size <<= 1) {
        for (int stride = size >> 1; stride > 0; stride >>= 1) {
            __syncthreads();
            const int j = t ^ stride;
            if (j > t) {
                float av = sv[t], bv = sv[j];
                int ai = si[t], bi = si[j];
                const bool before = (av > bv) || (av == bv && ai < bi);
                const bool dir = ((t & size) == 0);
                if (dir ? !before : before) { sv[t] = bv; si[t] = bi; sv[j] = av; si[j] = ai; }
            }
        }
    }
    __syncthreads();
    if (t < k) out[t] = si[t];
}

// fused: selidx[i] = idx1[idx2[i]]; remidx = ascending complement of selidx
__global__ void sel_complement_kernel(const int* __restrict__ idx1,
                                      const int* __restrict__ idx2,
                                      int* __restrict__ selidx,
                                      int* __restrict__ remidx)
{
    __shared__ int mask[1024];
    __shared__ int scan[1024];
    const int t = threadIdx.x;
    mask[t] = 0;
    __syncthreads();
    if (t < 256) {
        const int s = idx1[idx2[t]];
        selidx[t] = s;
        mask[s] = 1;
    }
    __syncthreads();
    const int keep = 1 - mask[t];
    scan[t] = keep;
    __syncthreads();
    for (int off = 1; off < 1024; off <<= 1) {
        int v = scan[t];
        if (t >= off) v += scan[t - off];
        __syncthreads();
        scan[t] = v;
        __syncthreads();
    }
    if (keep) remidx[scan[t] - 1] = t;
}

// fused merge prep: gather fp32 row + split hi/lo + row L2 norm.
__global__ __launch_bounds__(256) void prep_merge(
    const float* __restrict__ vf,
    const int* __restrict__ remidx, const int* __restrict__ selidx,
    float* __restrict__ rem_f, float* __restrict__ sel_f,
    short* __restrict__ remhi, short* __restrict__ remlo,
    short* __restrict__ selhi, short* __restrict__ sello,
    float* __restrict__ nr, float* __restrict__ ns)
{
    const int b = blockIdx.x, t = threadIdx.x;
    const bool isrem = (b < 768);
    const int r = isrem ? b : b - 768;
    const int sr = isrem ? remidx[r] : selidx[r];
    const float4* s = (const float4*)(vf + (long)sr * 4096);
    float* dstF = (isrem ? rem_f : sel_f) + (long)r * 4096;
    short* dhi = (isrem ? remhi : selhi) + (long)r * 4096;
    short* dlo = (isrem ? remlo : sello) + (long)r * 4096;
    for (int i = t; i < 1024; i += 256) {
        float4 f = s[i];
        *(float4*)&dstF[i * 4] = f;
        s16x4 h, l;
        sh2 p;
        p = splitf(f.x); h[0] = p.hi; l[0] = p.lo;
        p = splitf(f.y); h[1] = p.hi; l[1] = p.lo;
        p = splitf(f.z); h[2] = p.hi; l[2] = p.lo;
        p = splitf(f.w); h[3] = p.hi; l[3] = p.lo;
        *(s16x4*)&dhi[i * 4] = h;
        *(s16x4*)&dlo[i * 4] = l;
    }
    __syncthreads();
    float ss = 0.f;
    for (int c = t; c < 4096; c += 256) { float v = dstF[c]; ss += v * v; }
    __shared__ float red[256];
    red[t] = ss; __syncthreads();
    for (int off = 128; off; off >>= 1) { if (t < off) red[t] += red[t + off]; __syncthreads(); }
    if (!t) (isrem ? nr : ns)[r] = sqrtf(red[0]);
}

__global__ __launch_bounds__(256) void argmax_kernel(
    const float* __restrict__ S, const float* __restrict__ nr,
    const float* __restrict__ ns, int* __restrict__ best)
{
    const int r = blockIdx.x, t = threadIdx.x;
    float v = S[(long)r * 256 + t] / fmaxf(nr[r] * ns[t], 1e-8f);
    __shared__ float bv[256];
    __shared__ int bi[256];
    bv[t] = v; bi[t] = t; __syncthreads();
    for (int off = 128; off; off >>= 1) {
        if (t < off) {
            float ov = bv[t + off]; int oi = bi[t + off];
            if (ov > bv[t] || (ov == bv[t] && oi < bi[t])) { bv[t] = ov; bi[t] = oi; }
        }
        __syncthreads();
    }
    if (!t) best[r] = bi[0];
}

__global__ __launch_bounds__(256) void merge_kernel(
    const float* __restrict__ selb, const float* __restrict__ rem,
    const int* __restrict__ best, const float* __restrict__ nr,
    const float* __restrict__ ns, float* __restrict__ out)
{
    const int j = blockIdx.x, t = threadIdx.x;
    __shared__ int sbest[768];
    __shared__ float snr[768];
    __shared__ float red[256];
    for (int i = t; i < 768; i += 256) { sbest[i] = best[i]; snr[i] = nr[i]; }
    __syncthreads();
    float acc[16];
#pragma unroll
    for (int d = 0; d < 16; d++) acc[d] = 0.f;
    int cnt = 0; float smax = 0.f;
    const int base = t * 16;
    for (int i = 0; i < 768; i++) {
        if (sbest[i] == j) {
            cnt++;
            smax = fmaxf(smax, snr[i]);
            const float* rp = rem + (long)i * 4096 + base;
#pragma unroll
            for (int d = 0; d < 16; d += 4) {
                float4 x4 = *(const float4*)(rp + d);
                acc[d] += x4.x; acc[d + 1] += x4.y; acc[d + 2] += x4.z; acc[d + 3] += x4.w;
            }
        }
    }
    const float* sp = selb + (long)j * 4096 + base;
    float mean[16]; float ss = 0.f;
    const float denom = (float)(cnt + 1);
#pragma unroll
    for (int d = 0; d < 16; d++) { mean[d] = (sp[d] + acc[d]) / denom; ss += mean[d] * mean[d]; }
    red[t] = ss; __syncthreads();
    for (int off = 128; off; off >>= 1) { if (t < off) red[t] += red[t + off]; __syncthreads(); }
    const float nm = sqrtf(red[0]);
    const float mx = fmaxf(ns[j], cnt > 0 ? smax : 0.f);
    float* op = out + (long)j * 4096 + base;
#pragma unroll
    for (int d = 0; d < 16; d++) op[d] = (cnt > 0) ? (mean[d] / nm) * mx : sp[d];
}

// ============================================================================
// host orchestration
// ============================================================================
extern "C" void kernel_launch(void* const* d_in, const int* in_sizes, int n_in,
                              void* d_out, int out_size, void* d_ws, size_t ws_size,
                              hipStream_t stream)
{
    const float* vf   = (const float*)d_in[0];   // 1024 x 4096
    const float* te   = (const float*)d_in[1];   // 128 x 4096
    const float* inw  = (const float*)d_in[3];   // 4 x 12288 x 4096
    const float* inb  = (const float*)d_in[4];   // 4 x 12288
    const float* outw = (const float*)d_in[5];   // 4 x 4096 x 4096
    const float* outb = (const float*)d_in[6];   // 4 x 4096
    const float* w1   = (const float*)d_in[7];   // 2 x 2048 x 4096
    const float* b1   = (const float*)d_in[8];   // 2 x 2048
    const float* w2   = (const float*)d_in[9];   // 2 x 2048
    const float* b2   = (const float*)d_in[10];  // 2
    float* out = (float*)d_out;                  // 256 x 4096
    char* base = (char*)d_ws;

    char* qkR = base;                 // 37,748,736 : qk split / probs / partials
    char* vTR = base + 37748736;      // 18,874,368 : vT split
    char* scR = vTR + 18874368;       // 37,748,736 : comb/scor/o/g/hbuf/final
    float* smalls = (float*)(scR + 37748736);
    // large split-K partial scratch (ws ~3 GiB per poison WRITE_SIZE)
    float* pbig = (float*)(base + 134217728);    // 128 MB offset, <=67 MB used

    short* qkhi = (short*)qkR;
    short* qklo = (short*)(qkR + 18874368);
    short* vThi = (short*)vTR;
    short* vTlo = (short*)(vTR + 9437184);
    float* hbuf = (float*)scR;

    float* logits = smalls;
    float* nr     = smalls + 1024;
    float* ns     = smalls + 1792;
    int* idx1   = (int*)(smalls + 2048);
    int* idx2   = (int*)(smalls + 2560);
    int* selidx = (int*)(smalls + 2816);
    int* remidx = (int*)(smalls + 3072);
    int* best   = (int*)(smalls + 3840);

    const float scl = (float)(1.0 / sqrt(512.0));
    const int NOSKIP = 1 << 30;

    for (int m = 0; m < 2; m++) {
        const int Mq  = m ? 512 : 1024;
        const int Mkv = m ? 640 : 1152;
        const float* Wqkv = inw + (size_t)(2 * m) * 12288 * 4096;
        const float* bqkv = inb + (size_t)(2 * m) * 12288;
        const float* ow = outw + (size_t)(2 * m) * 4096 * 4096;
        const float* ob = outb + (size_t)(2 * m) * 4096;

        // ---- comb split (fused vf+te) ----
        short* chi = (short*)scR;
        short* clo = (short*)(scR + (size_t)Mkv * 4096 * 2);
        split_comb<<<Mkv, 256, 0, stream>>>(vf, te, m ? idx1 : nullptr, Mq, chi, clo);
        // ---- fused in-proj: q,k -> qk split; v -> vT split (transposed) ----
        if (m == 0) {
            mfma_gemm256<<<dim3(48, 5, 1), 512, 0, stream>>>(
                chi, clo, 4096, Wqkv, 4096, qkhi, qklo, vThi, vTlo,
                8192, 1152, 4096, 1152, bqkv, 1024);
        } else {
            mfma_gemm<0, 2, false><<<dim3(96, Mkv / 128, 1), 256, 0, stream>>>(
                chi, clo, 4096, 0, Wqkv, nullptr, nullptr, 4096, 0,
                nullptr, qkhi, qklo, vThi, vTlo, 8192, 1152, 0, 4096, 1, 1.f,
                bqkv, 512);
        }
        // ---- scores[h] = scl * q_h @ k_h^T (fp32) ----
        float* scor = (float*)(m ? (scR + 10485760) : scR);
        if (m == 0) {
            mfma_gemm<1, 0, false><<<dim3(9, 8, 8), 256, 0, stream>>>(
                qkhi, qklo, 8192, 512, nullptr, qkhi + 4096, qklo + 4096, 8192, 512,
                scor, nullptr, nullptr, nullptr, nullptr, 1152, 0, (long)Mq * Mkv,
                512, 1, scl, nullptr, NOSKIP);
        } else {
            // SK=2 -> 320 blocks (was 160, half CUs idle)
            mfma_gemm<1, 0, false><<<dim3(5, 4, 16), 256, 0, stream>>>(
                qkhi, qklo, 8192, 512, nullptr, qkhi + 4096, qklo + 4096, 8192, 512,
                pbig, nullptr, nullptr, nullptr, nullptr, 640, 0, 327680,
                512, 2, scl, nullptr, NOSKIP);
            reduce_k<0, false><<<dim3(320, 8), 256, 0, stream>>>(
                pbig, 327680, 2, 327680, 640, 640, 327680, scor, nullptr, nullptr, nullptr);
        }
        // ---- softmax -> split probs ----
        short* phi = (short*)qkR;
        short* plo = (short*)(qkR + (size_t)8 * Mq * Mkv * 2);
        softmax_split<<<8 * Mq, 256, 0, stream>>>(scor, phi, plo, Mkv);
        // ---- PV: o = probs @ vT^T -> obuf split (split-K to fill CUs) ----
        short* ohi = (short*)scR;
        short* olo = (short*)(scR + (size_t)Mq * 4096 * 2);
        if (m == 0) {
            // SK=2 -> 512 blocks (was 256)
            mfma_gemm<1, 0, false><<<dim3(4, 8, 16), 256, 0, stream>>>(
                phi, plo, Mkv, (long)Mq * Mkv, nullptr, vThi, vTlo, 1152, 512L * 1152,
                pbig, nullptr, nullptr, nullptr, nullptr, 512, 0, 524288,
                Mkv, 2, 1.f, nullptr, NOSKIP);
            reduce_k<1, false><<<dim3(512, 8), 256, 0, stream>>>(
                pbig, 524288, 2, 524288, 512, 4096, 512, nullptr, ohi, olo, nullptr);
        } else {
            // SK=4 -> 512 blocks (was 256 at SK=2); Kc = 640/4 = 160 (5x32)
            mfma_gemm<1, 0, false><<<dim3(4, 4, 32), 256, 0, stream>>>(
                phi, plo, Mkv, (long)Mq * Mkv, nullptr, vThi, vTlo, 1152, 512L * 1152,
                pbig, nullptr, nullptr, nullptr, nullptr, 512, 0, 262144,
                Mkv, 4, 1.f, nullptr, NOSKIP);
            reduce_k<1, false><<<dim3(256, 8), 256, 0, stream>>>(
                pbig, 262144, 4, 262144, 512, 4096, 512, nullptr, ohi, olo, nullptr);
        }
        // ---- out-proj: g = o @ ow^T + ob (256^2 split-K -> 256 blocks) ----
        short* ghi = (short*)(scR + (size_t)Mq * 4096 * 4);
        short* glo = (short*)(scR + (size_t)Mq * 4096 * 6);
        {
            const int SKg = m ? 8 : 4;
            const long zst = (long)Mq * 4096;
            mfma_gemm256sk<<<dim3(16, Mq / 256, SKg), 512, 0, stream>>>(
                ohi, olo, 4096, ow, 4096, pbig, zst, 4096, 4096, SKg);
            reduce_k<1, false><<<dim3((int)(zst / 1024), 1), 256, 0, stream>>>(
                pbig, zst, SKg, (int)zst, 4096, 4096, 0, nullptr, ghi, glo, ob);
        }
        // ---- MLP: h = relu(g @ w1^T + b1) (256^2 split-K -> 256 blocks) ----
        {
            const int SKm = m ? 16 : 8;
            const long zst = (long)Mq * 2048;
            mfma_gemm256sk<<<dim3(8, Mq / 256, SKm), 512, 0, stream>>>(
                ghi, glo, 4096, w1 + (size_t)m * 2048 * 4096, 4096,
                pbig, zst, 2048, 4096, SKm);
            reduce_k<0, true><<<dim3((int)(zst / 1024), 1), 256, 0, stream>>>(
                pbig, zst, SKm, (int)zst, 2048, 2048, 0, hbuf, nullptr, nullptr,
                b1 + (size_t)m * 2048);
        }
        gemv_kernel<<<Mq, 256, 0, stream>>>(hbuf, w2 + (size_t)m * 2048, b2 + m, logits);
        if (m == 0) topk_kernel<<<1, 1024, 0, stream>>>(logits, 1024, 512, idx1);
        else        topk_kernel<<<1, 512, 0, stream>>>(logits, 512, 256, idx2);
    }

    // ---- merge phase ----
    short* remhi = (short*)scR;
    short* remlo = (short*)(scR + 6291456);
    short* selhi = (short*)(scR + 12582912);
    short* sello = (short*)(scR + 14680064);
    float* rem_f = (float*)(scR + 16777216);
    float* sel_f = (float*)(scR + 29360128);
    float* Smat  = (float*)(scR + 33554432);

    sel_complement_kernel<<<1, 1024, 0, stream>>>(idx1, idx2, selidx, remidx);
    prep_merge<<<1024, 256, 0, stream>>>(vf, remidx, selidx, rem_f, sel_f,
                                         remhi, remlo, selhi, sello, nr, ns);
    // S = rem @ selb^T (split-K=16 -> 192 blocks; Kc = 256)
    {
        float* Ps = (float*)qkR;
        mfma_gemm<1, 0, false><<<dim3(2, 6, 16), 256, 0, stream>>>(
            remhi, remlo, 4096, 0, nullptr, selhi, sello, 4096, 0,
            Ps, nullptr, nullptr, nullptr, nullptr, 256, 0, 196608,
            4096, 16, 1.f, nullptr, NOSKIP);
        reduce_k<0, false><<<dim3(192, 1), 256, 0, stream>>>(
            Ps, 196608, 16, 196608, 256, 256, 0, Smat, nullptr, nullptr, nullptr);
    }
    argmax_kernel<<<768, 256, 0, stream>>>(Smat, nr, ns, best);
    merge_kernel<<<256, 256, 0, stream>>>(sel_f, rem_f, best, nr, ns, out);
}

// Round 14
// 1226.858 us; speedup vs baseline: 1.0267x; 1.0267x over previous
//
#include <hip/hip_runtime.h>
#include <hip/hip_bf16.h>
#include <math.h>
#include <stdint.h>

typedef __attribute__((ext_vector_type(4))) float f32x4;
typedef __attribute__((ext_vector_type(8))) short s16x8;
typedef __attribute__((ext_vector_type(4))) short s16x4;

struct sh2 { short hi, lo; };

// fp32 -> bf16 hi/lo split. hi = bf16(x) (RNE), lo = bf16(x - hi).
__device__ __forceinline__ sh2 splitf(float x)
{
    __hip_bfloat16 h = __float2bfloat16(x);
    float hf = __bfloat162float(h);
    __hip_bfloat16 l = __float2bfloat16(x - hf);
    sh2 r;
    r.hi = __builtin_bit_cast(short, h);
    r.lo = __builtin_bit_cast(short, l);
    return r;
}

__device__ __forceinline__ void split8(const float4& a, const float4& b,
                                       s16x8& h, s16x8& l)
{
    sh2 p;
    p = splitf(a.x); h[0] = p.hi; l[0] = p.lo;
    p = splitf(a.y); h[1] = p.hi; l[1] = p.lo;
    p = splitf(a.z); h[2] = p.hi; l[2] = p.lo;
    p = splitf(a.w); h[3] = p.hi; l[3] = p.lo;
    p = splitf(b.x); h[4] = p.hi; l[4] = p.lo;
    p = splitf(b.y); h[5] = p.hi; l[5] = p.lo;
    p = splitf(b.z); h[6] = p.hi; l[6] = p.lo;
    p = splitf(b.w); h[7] = p.hi; l[7] = p.lo;
}

// async global->LDS 16B copy (wave-uniform LDS base; lane writes base+lane*16)
typedef const __attribute__((address_space(1))) void gvoid_t;
typedef __attribute__((address_space(3))) void lvoid_t;
__device__ __forceinline__ void gld_lds16(const void* g, void* l)
{
    __builtin_amdgcn_global_load_lds((gvoid_t*)(uintptr_t)g,
                                     (lvoid_t*)(uintptr_t)l, 16, 0, 0);
}

// ============================================================================
// split-bf16 MFMA GEMM (128x128 tile): C = alpha*(A @ B^T) [+bias] [ReLU]
// A pre-split. BF=0: B fp32 (N x K), split inline. BF=1: B pre-split.
// EPI=0 fp32 C [RELU]; EPI=1 split C; EPI=2 in-proj. SK>1: raw fp32 partials.
// 2-phase dbuf; chunk-XOR bank swizzle on SOURCE; XCD block swizzle.
// ============================================================================
template<int BF, int EPI, bool RELU>
__global__ __launch_bounds__(256, 2) void mfma_gemm(
    const short* __restrict__ Ahi, const short* __restrict__ Alo, int lda, long sA,
    const float* __restrict__ Bf, const short* __restrict__ Bhi,
    const short* __restrict__ Blo, int ldb, long sB,
    float* __restrict__ Cf, short* __restrict__ Chi, short* __restrict__ Clo,
    short* __restrict__ Thi, short* __restrict__ Tlo, int ldc, int ldT, long sC,
    int K, int SK, float alpha, const float* __restrict__ bias, int mskip)
{
    __shared__ short SH[2][16384];
    const int zf = blockIdx.z;
    const int sk = (SK > 1) ? (zf % SK) : 0;
    const int bz = (SK > 1) ? (zf / SK) : zf;
    const int Kc = K / SK;
    const int kb = sk * Kc;
    Ahi += (long)bz * sA; Alo += (long)bz * sA;
    if (BF == 0) Bf += (long)bz * sB; else { Bhi += (long)bz * sB; Blo += (long)bz * sB; }
    const long cofs = (long)((SK > 1) ? zf : bz) * sC;

    const int GX = gridDim.x, GY = gridDim.y;
    const int nwg = GX * GY;
    const int bid = blockIdx.x + GX * blockIdx.y;
    const int q8 = nwg >> 3, r8 = nwg & 7;
    const int xcd = bid & 7, sl = bid >> 3;
    const int t = (xcd < r8) ? (xcd * (q8 + 1) + sl)
                             : (r8 * (q8 + 1) + (xcd - r8) * q8 + sl);
    const int m0 = (t % GY) * 128, n0 = (t / GY) * 128;

    if (EPI == 2 && n0 < 4096 && m0 >= mskip) return;

    const int tid = threadIdx.x;
    const int lane = tid & 63, wave = tid >> 6;
    const int wr = (wave >> 1) * 64, wc = (wave & 1) * 64;
    const int lrow = lane & 15, lk = lane >> 4;
    const int cswz8 = (lk ^ ((lrow >> 1) & 3)) << 3;

    const int rA0 = wave * 16 + (lane >> 2);
    const int rA1 = rA0 + 64;
    const int sc0 = ((lane & 3) ^ ((rA0 >> 1) & 3)) * 8;
    const int sc1 = ((lane & 3) ^ ((rA1 >> 1) & 3)) * 8;
    const long gA0 = (long)(m0 + rA0) * lda + sc0;
    const long gA1 = (long)(m0 + rA1) * lda + sc1;
    long gB0 = 0, gB1 = 0;
    if (BF == 1) {
        gB0 = (long)(n0 + rA0) * ldb + sc0;
        gB1 = (long)(n0 + rA1) * ldb + sc1;
    }
    const int lw0 = wave * 512, lw1 = wave * 512 + 2048;

    const int brow = tid & 127;
    const int bkc0 = (tid >> 7) * 8;
    const int bkc1 = bkc0 + 16;
    const int bw0 = brow * 32 + (((bkc0 >> 3) ^ ((brow >> 1) & 3)) << 3);
    const int bw1 = brow * 32 + (((bkc1 >> 3) ^ ((brow >> 1) & 3)) << 3);
    const float* bpr = (BF == 0) ? Bf + (long)(n0 + brow) * ldb : nullptr;

    f32x4 acc[4][4];
#pragma unroll
    for (int i = 0; i < 4; i++)
#pragma unroll
        for (int j = 0; j < 4; j++) acc[i][j] = (f32x4){0.f, 0.f, 0.f, 0.f};

    float4 rb0a, rb0b, rb1a, rb1b;

    {
        short* S = &SH[0][0];
        gld_lds16(Ahi + gA0 + kb, S + lw0);
        gld_lds16(Ahi + gA1 + kb, S + lw1);
        gld_lds16(Alo + gA0 + kb, S + 4096 + lw0);
        gld_lds16(Alo + gA1 + kb, S + 4096 + lw1);
        if constexpr (BF == 1) {
            gld_lds16(Bhi + gB0 + kb, S + 8192 + lw0);
            gld_lds16(Bhi + gB1 + kb, S + 8192 + lw1);
            gld_lds16(Blo + gB0 + kb, S + 12288 + lw0);
            gld_lds16(Blo + gB1 + kb, S + 12288 + lw1);
        } else {
            rb0a = *(const float4*)(bpr + kb + bkc0);
            rb0b = *(const float4*)(bpr + kb + bkc0 + 4);
            rb1a = *(const float4*)(bpr + kb + bkc1);
            rb1b = *(const float4*)(bpr + kb + bkc1 + 4);
            s16x8 h, l;
            split8(rb0a, rb0b, h, l);
            *(s16x8*)&S[8192 + bw0] = h;
            *(s16x8*)&S[12288 + bw0] = l;
            split8(rb1a, rb1b, h, l);
            *(s16x8*)&S[8192 + bw1] = h;
            *(s16x8*)&S[12288 + bw1] = l;
        }
    }
    __syncthreads();

    int cur = 0;
    const int kend = kb + Kc;
    for (int k0 = kb; k0 < kend; k0 += 32) {
        const int kn = k0 + 32;
        const bool nx = (kn < kend);
        short* SN = &SH[cur ^ 1][0];
        if (nx) {
            gld_lds16(Ahi + gA0 + kn, SN + lw0);
            gld_lds16(Ahi + gA1 + kn, SN + lw1);
            gld_lds16(Alo + gA0 + kn, SN + 4096 + lw0);
            gld_lds16(Alo + gA1 + kn, SN + 4096 + lw1);
            if constexpr (BF == 1) {
                gld_lds16(Bhi + gB0 + kn, SN + 8192 + lw0);
                gld_lds16(Bhi + gB1 + kn, SN + 8192 + lw1);
                gld_lds16(Blo + gB0 + kn, SN + 12288 + lw0);
                gld_lds16(Blo + gB1 + kn, SN + 12288 + lw1);
            } else {
                rb0a = *(const float4*)(bpr + kn + bkc0);
                rb0b = *(const float4*)(bpr + kn + bkc0 + 4);
                rb1a = *(const float4*)(bpr + kn + bkc1);
                rb1b = *(const float4*)(bpr + kn + bkc1 + 4);
            }
        }
        const short* S = &SH[cur][0];
        s16x8 ah[4], al[4], bh[4], bl[4];
#pragma unroll
        for (int m = 0; m < 4; m++) {
            const int idx = (wr + m * 16 + lrow) * 32 + cswz8;
            ah[m] = *(const s16x8*)&S[idx];
            al[m] = *(const s16x8*)&S[4096 + idx];
        }
#pragma unroll
        for (int n = 0; n < 4; n++) {
            const int idx = (wc + n * 16 + lrow) * 32 + cswz8;
            bh[n] = *(const s16x8*)&S[8192 + idx];
            bl[n] = *(const s16x8*)&S[12288 + idx];
        }
#pragma unroll
        for (int n = 0; n < 4; n++)
#pragma unroll
            for (int m = 0; m < 4; m++)
                acc[m][n] = __builtin_amdgcn_mfma_f32_16x16x32_bf16(ah[m], bh[n], acc[m][n], 0, 0, 0);
#pragma unroll
        for (int n = 0; n < 4; n++)
#pragma unroll
            for (int m = 0; m < 4; m++)
                acc[m][n] = __builtin_amdgcn_mfma_f32_16x16x32_bf16(ah[m], bl[n], acc[m][n], 0, 0, 0);
#pragma unroll
        for (int n = 0; n < 4; n++)
#pragma unroll
            for (int m = 0; m < 4; m++)
                acc[m][n] = __builtin_amdgcn_mfma_f32_16x16x32_bf16(al[m], bh[n], acc[m][n], 0, 0, 0);
        if (BF == 0 && nx) {
            s16x8 h, l;
            split8(rb0a, rb0b, h, l);
            *(s16x8*)&SN[8192 + bw0] = h;
            *(s16x8*)&SN[12288 + bw0] = l;
            split8(rb1a, rb1b, h, l);
            *(s16x8*)&SN[8192 + bw1] = h;
            *(s16x8*)&SN[12288 + bw1] = l;
        }
        __syncthreads();
        cur ^= 1;
    }
#pragma unroll
    for (int n = 0; n < 4; n++) {
        const int col = n0 + wc + n * 16 + lrow;
        const float bv = (SK == 1 && bias) ? bias[col] : 0.f;
#pragma unroll
        for (int m = 0; m < 4; m++) {
            const int row = m0 + wr + m * 16 + lk * 4;
            if (SK > 1) {
#pragma unroll
                for (int r = 0; r < 4; r++)
                    Cf[cofs + (long)(row + r) * ldc + col] = acc[m][n][r] * alpha;
            } else if constexpr (EPI == 0) {
#pragma unroll
                for (int r = 0; r < 4; r++) {
                    float v = acc[m][n][r] * alpha + bv;
                    if (RELU) v = fmaxf(v, 0.f);
                    Cf[cofs + (long)(row + r) * ldc + col] = v;
                }
            } else if constexpr (EPI == 1) {
#pragma unroll
                for (int r = 0; r < 4; r++) {
                    float v = acc[m][n][r] * alpha + bv;
                    sh2 p = splitf(v);
                    Chi[cofs + (long)(row + r) * ldc + col] = p.hi;
                    Clo[cofs + (long)(row + r) * ldc + col] = p.lo;
                }
            } else {
                if (n0 < 8192) {
#pragma unroll
                    for (int r = 0; r < 4; r++) {
                        float v = acc[m][n][r] + bv;
                        sh2 p = splitf(v);
                        Chi[(long)(row + r) * ldc + col] = p.hi;
                        Clo[(long)(row + r) * ldc + col] = p.lo;
                    }
                } else {
                    s16x4 h4, l4;
#pragma unroll
                    for (int r = 0; r < 4; r++) {
                        float v = acc[m][n][r] + bv;
                        sh2 p = splitf(v);
                        h4[r] = p.hi; l4[r] = p.lo;
                    }
                    const long tof = (long)(col - 8192) * ldT + row;
                    *(s16x4*)&Thi[tof] = h4;
                    *(s16x4*)&Tlo[tof] = l4;
                }
            }
        }
    }
}

// ============================================================================
// 256x256-tile split-bf16 GEMM, BF=0, EPI=2 (in-proj), 8 waves, 128 KB LDS.
// mskip: dead-block exit for q-cols x te-rows.
// ============================================================================
__global__ __launch_bounds__(512, 2) void mfma_gemm256(
    const short* __restrict__ Ahi, const short* __restrict__ Alo, int lda,
    const float* __restrict__ Bf, int ldb,
    short* __restrict__ Chi, short* __restrict__ Clo,
    short* __restrict__ Thi, short* __restrict__ Tlo, int ldc, int ldT,
    int K, int Mreal, const float* __restrict__ bias, int mskip)
{
    __shared__ short SH[2][32768];

    const int GX = gridDim.x, GY = gridDim.y;
    const int nwg = GX * GY;
    const int bid = blockIdx.x + GX * blockIdx.y;
    const int q8 = nwg >> 3, r8 = nwg & 7;
    const int xcd = bid & 7, sl = bid >> 3;
    const int t = (xcd < r8) ? (xcd * (q8 + 1) + sl)
                             : (r8 * (q8 + 1) + (xcd - r8) * q8 + sl);
    const int m0 = (t % GY) * 256, n0 = (t / GY) * 256;

    if (n0 < 4096 && m0 >= mskip) return;

    const int tid = threadIdx.x;
    const int lane = tid & 63, wave = tid >> 6;
    const int wr = (wave >> 1) * 64, wc = (wave & 1) * 128;
    const int lrow = lane & 15, lk = lane >> 4;
    const int cswz8 = (lk ^ ((lrow >> 1) & 3)) << 3;

    const int rA0 = wave * 32 + (lane >> 2);
    const int rA1 = rA0 + 16;
    const int sc0 = ((lane & 3) ^ ((rA0 >> 1) & 3)) * 8;
    const int sc1 = ((lane & 3) ^ ((rA1 >> 1) & 3)) * 8;
    const long gA0 = (long)(m0 + rA0) * lda + sc0;
    const long gA1 = (long)(m0 + rA1) * lda + sc1;
    const int lw0 = wave * 1024, lw1 = wave * 1024 + 512;

    const int brow = tid & 255;
    const int bk = (tid >> 8) * 16;
    const int bw0 = brow * 32 + ((((bk >> 3) + 0) ^ ((brow >> 1) & 3)) << 3);
    const int bw1 = brow * 32 + ((((bk >> 3) + 1) ^ ((brow >> 1) & 3)) << 3);
    const float* bpr = Bf + (long)(n0 + brow) * ldb + bk;

    f32x4 acc[4][8];
#pragma unroll
    for (int i = 0; i < 4; i++)
#pragma unroll
        for (int j = 0; j < 8; j++) acc[i][j] = (f32x4){0.f, 0.f, 0.f, 0.f};

    float4 rb0, rb1, rb2, rb3;

    {
        short* S = &SH[0][0];
        gld_lds16(Ahi + gA0, S + lw0);
        gld_lds16(Ahi + gA1, S + lw1);
        gld_lds16(Alo + gA0, S + 8192 + lw0);
        gld_lds16(Alo + gA1, S + 8192 + lw1);
        rb0 = *(const float4*)(bpr + 0);
        rb1 = *(const float4*)(bpr + 4);
        rb2 = *(const float4*)(bpr + 8);
        rb3 = *(const float4*)(bpr + 12);
        s16x8 h, l;
        split8(rb0, rb1, h, l);
        *(s16x8*)&S[16384 + bw0] = h;
        *(s16x8*)&S[24576 + bw0] = l;
        split8(rb2, rb3, h, l);
        *(s16x8*)&S[16384 + bw1] = h;
        *(s16x8*)&S[24576 + bw1] = l;
    }
    __syncthreads();

    int cur = 0;
    for (int k0 = 0; k0 < K; k0 += 32) {
        const int kn = k0 + 32;
        const bool nx = (kn < K);
        short* SN = &SH[cur ^ 1][0];
        if (nx) {
            gld_lds16(Ahi + gA0 + kn, SN + lw0);
            gld_lds16(Ahi + gA1 + kn, SN + lw1);
            gld_lds16(Alo + gA0 + kn, SN + 8192 + lw0);
            gld_lds16(Alo + gA1 + kn, SN + 8192 + lw1);
            rb0 = *(const float4*)(bpr + kn + 0);
            rb1 = *(const float4*)(bpr + kn + 4);
            rb2 = *(const float4*)(bpr + kn + 8);
            rb3 = *(const float4*)(bpr + kn + 12);
        }
        const short* S = &SH[cur][0];
        s16x8 ah[4], al[4];
#pragma unroll
        for (int m = 0; m < 4; m++) {
            const int idx = (wr + m * 16 + lrow) * 32 + cswz8;
            ah[m] = *(const s16x8*)&S[idx];
            al[m] = *(const s16x8*)&S[8192 + idx];
        }
#pragma unroll
        for (int np = 0; np < 4; np++) {
            s16x8 bh[2], bl[2];
#pragma unroll
            for (int j = 0; j < 2; j++) {
                const int idx = (wc + (np * 2 + j) * 16 + lrow) * 32 + cswz8;
                bh[j] = *(const s16x8*)&S[16384 + idx];
                bl[j] = *(const s16x8*)&S[24576 + idx];
            }
#pragma unroll
            for (int j = 0; j < 2; j++)
#pragma unroll
                for (int m = 0; m < 4; m++)
                    acc[m][np * 2 + j] = __builtin_amdgcn_mfma_f32_16x16x32_bf16(ah[m], bh[j], acc[m][np * 2 + j], 0, 0, 0);
#pragma unroll
            for (int j = 0; j < 2; j++)
#pragma unroll
                for (int m = 0; m < 4; m++)
                    acc[m][np * 2 + j] = __builtin_amdgcn_mfma_f32_16x16x32_bf16(ah[m], bl[j], acc[m][np * 2 + j], 0, 0, 0);
#pragma unroll
            for (int j = 0; j < 2; j++)
#pragma unroll
                for (int m = 0; m < 4; m++)
                    acc[m][np * 2 + j] = __builtin_amdgcn_mfma_f32_16x16x32_bf16(al[m], bh[j], acc[m][np * 2 + j], 0, 0, 0);
        }
        if (nx) {
            s16x8 h, l;
            split8(rb0, rb1, h, l);
            *(s16x8*)&SN[16384 + bw0] = h;
            *(s16x8*)&SN[24576 + bw0] = l;
            split8(rb2, rb3, h, l);
            *(s16x8*)&SN[16384 + bw1] = h;
            *(s16x8*)&SN[24576 + bw1] = l;
        }
        __syncthreads();
        cur ^= 1;
    }
#pragma unroll
    for (int n = 0; n < 8; n++) {
        const int col = n0 + wc + n * 16 + lrow;
        const float bv = bias[col];
#pragma unroll
        for (int m = 0; m < 4; m++) {
            const int row = m0 + wr + m * 16 + lk * 4;
            if (row < Mreal) {
                if (n0 < 8192) {
#pragma unroll
                    for (int r = 0; r < 4; r++) {
                        float v = acc[m][n][r] + bv;
                        sh2 p = splitf(v);
                        Chi[(long)(row + r) * ldc + col] = p.hi;
                        Clo[(long)(row + r) * ldc + col] = p.lo;
                    }
                } else {
                    s16x4 h4, l4;
#pragma unroll
                    for (int r = 0; r < 4; r++) {
                        float v = acc[m][n][r] + bv;
                        sh2 p = splitf(v);
                        h4[r] = p.hi; l4[r] = p.lo;
                    }
                    const long tof = (long)(col - 8192) * ldT + row;
                    *(s16x4*)&Thi[tof] = h4;
                    *(s16x4*)&Tlo[tof] = l4;
                }
            }
        }
    }
}

// ============================================================================
// 256x256-tile split-bf16 GEMM with split-K, BF=0 (fp32 B), raw fp32 partials.
// ============================================================================
__global__ __launch_bounds__(512, 2) void mfma_gemm256sk(
    const short* __restrict__ Ahi, const short* __restrict__ Alo, int lda,
    const float* __restrict__ Bf, int ldb,
    float* __restrict__ P, long zstride, int ldp,
    int K, int SK)
{
    __shared__ short SH[2][32768];

    const int sk = blockIdx.z;
    const int Kc = K / SK;
    const int kb = sk * Kc;

    const int GX = gridDim.x, GY = gridDim.y;
    const int nwg = GX * GY;
    const int bid = blockIdx.x + GX * blockIdx.y;
    const int q8 = nwg >> 3, r8 = nwg & 7;
    const int xcd = bid & 7, sl = bid >> 3;
    const int t = (xcd < r8) ? (xcd * (q8 + 1) + sl)
                             : (r8 * (q8 + 1) + (xcd - r8) * q8 + sl);
    const int m0 = (t % GY) * 256, n0 = (t / GY) * 256;

    const int tid = threadIdx.x;
    const int lane = tid & 63, wave = tid >> 6;
    const int wr = (wave >> 1) * 64, wc = (wave & 1) * 128;
    const int lrow = lane & 15, lk = lane >> 4;
    const int cswz8 = (lk ^ ((lrow >> 1) & 3)) << 3;

    const int rA0 = wave * 32 + (lane >> 2);
    const int rA1 = rA0 + 16;
    const int sc0 = ((lane & 3) ^ ((rA0 >> 1) & 3)) * 8;
    const int sc1 = ((lane & 3) ^ ((rA1 >> 1) & 3)) * 8;
    const long gA0 = (long)(m0 + rA0) * lda + sc0;
    const long gA1 = (long)(m0 + rA1) * lda + sc1;
    const int lw0 = wave * 1024, lw1 = wave * 1024 + 512;

    const int brow = tid & 255;
    const int bk = (tid >> 8) * 16;
    const int bw0 = brow * 32 + ((((bk >> 3) + 0) ^ ((brow >> 1) & 3)) << 3);
    const int bw1 = brow * 32 + ((((bk >> 3) + 1) ^ ((brow >> 1) & 3)) << 3);
    const float* bpr = Bf + (long)(n0 + brow) * ldb + bk;

    f32x4 acc[4][8];
#pragma unroll
    for (int i = 0; i < 4; i++)
#pragma unroll
        for (int j = 0; j < 8; j++) acc[i][j] = (f32x4){0.f, 0.f, 0.f, 0.f};

    float4 rb0, rb1, rb2, rb3;

    {
        short* S = &SH[0][0];
        gld_lds16(Ahi + gA0 + kb, S + lw0);
        gld_lds16(Ahi + gA1 + kb, S + lw1);
        gld_lds16(Alo + gA0 + kb, S + 8192 + lw0);
        gld_lds16(Alo + gA1 + kb, S + 8192 + lw1);
        rb0 = *(const float4*)(bpr + kb + 0);
        rb1 = *(const float4*)(bpr + kb + 4);
        rb2 = *(const float4*)(bpr + kb + 8);
        rb3 = *(const float4*)(bpr + kb + 12);
        s16x8 h, l;
        split8(rb0, rb1, h, l);
        *(s16x8*)&S[16384 + bw0] = h;
        *(s16x8*)&S[24576 + bw0] = l;
        split8(rb2, rb3, h, l);
        *(s16x8*)&S[16384 + bw1] = h;
        *(s16x8*)&S[24576 + bw1] = l;
    }
    __syncthreads();

    int cur = 0;
    const int kend = kb + Kc;
    for (int k0 = kb; k0 < kend; k0 += 32) {
        const int kn = k0 + 32;
        const bool nx = (kn < kend);
        short* SN = &SH[cur ^ 1][0];
        if (nx) {
            gld_lds16(Ahi + gA0 + kn, SN + lw0);
            gld_lds16(Ahi + gA1 + kn, SN + lw1);
            gld_lds16(Alo + gA0 + kn, SN + 8192 + lw0);
            gld_lds16(Alo + gA1 + kn, SN + 8192 + lw1);
            rb0 = *(const float4*)(bpr + kn + 0);
            rb1 = *(const float4*)(bpr + kn + 4);
            rb2 = *(const float4*)(bpr + kn + 8);
            rb3 = *(const float4*)(bpr + kn + 12);
        }
        const short* S = &SH[cur][0];
        s16x8 ah[4], al[4];
#pragma unroll
        for (int m = 0; m < 4; m++) {
            const int idx = (wr + m * 16 + lrow) * 32 + cswz8;
            ah[m] = *(const s16x8*)&S[idx];
            al[m] = *(const s16x8*)&S[8192 + idx];
        }
#pragma unroll
        for (int np = 0; np < 4; np++) {
            s16x8 bh[2], bl[2];
#pragma unroll
            for (int j = 0; j < 2; j++) {
                const int idx = (wc + (np * 2 + j) * 16 + lrow) * 32 + cswz8;
                bh[j] = *(const s16x8*)&S[16384 + idx];
                bl[j] = *(const s16x8*)&S[24576 + idx];
            }
#pragma unroll
            for (int j = 0; j < 2; j++)
#pragma unroll
                for (int m = 0; m < 4; m++)
                    acc[m][np * 2 + j] = __builtin_amdgcn_mfma_f32_16x16x32_bf16(ah[m], bh[j], acc[m][np * 2 + j], 0, 0, 0);
#pragma unroll
            for (int j = 0; j < 2; j++)
#pragma unroll
                for (int m = 0; m < 4; m++)
                    acc[m][np * 2 + j] = __builtin_amdgcn_mfma_f32_16x16x32_bf16(ah[m], bl[j], acc[m][np * 2 + j], 0, 0, 0);
#pragma unroll
            for (int j = 0; j < 2; j++)
#pragma unroll
                for (int m = 0; m < 4; m++)
                    acc[m][np * 2 + j] = __builtin_amdgcn_mfma_f32_16x16x32_bf16(al[m], bh[j], acc[m][np * 2 + j], 0, 0, 0);
        }
        if (nx) {
            s16x8 h, l;
            split8(rb0, rb1, h, l);
            *(s16x8*)&SN[16384 + bw0] = h;
            *(s16x8*)&SN[24576 + bw0] = l;
            split8(rb2, rb3, h, l);
            *(s16x8*)&SN[16384 + bw1] = h;
            *(s16x8*)&SN[24576 + bw1] = l;
        }
        __syncthreads();
        cur ^= 1;
    }
    const long zofs = (long)sk * zstride;
#pragma unroll
    for (int n = 0; n < 8; n++) {
        const int col = n0 + wc + n * 16 + lrow;
#pragma unroll
        for (int m = 0; m < 4; m++) {
            const int row = m0 + wr + m * 16 + lk * 4;
#pragma unroll
            for (int r = 0; r < 4; r++)
                P[zofs + (long)(row + r) * ldp + col] = acc[m][n][r];
        }
    }
}

// ============================================================================
// split-K reducer: sums SK partials in fixed order + epilogue
// ============================================================================
template<int EPI, bool RELU>
__global__ __launch_bounds__(256) void reduce_k(
    const float* __restrict__ P, long zstride, int SK, int total,
    int Ninner, int ldc, int colstep,
    float* __restrict__ Cf, short* __restrict__ Chi, short* __restrict__ Clo,
    const float* __restrict__ bias)
{
    const int bz = blockIdx.y;
    const long pbase = (long)bz * SK * zstride;
    const int e = (blockIdx.x * 256 + threadIdx.x) * 4;
    if (e >= total) return;
    const float* p = P + pbase + e;
    float4 s = *(const float4*)p;
    for (int k = 1; k < SK; k++) {
        float4 tv = *(const float4*)(p + (long)k * zstride);
        s.x += tv.x; s.y += tv.y; s.z += tv.z; s.w += tv.w;
    }
    const int r = e / Ninner, c = e % Ninner;
    const int col0 = colstep * bz + c;
    const long ob = (long)r * ldc + col0;
    float v[4] = {s.x, s.y, s.z, s.w};
#pragma unroll
    for (int j = 0; j < 4; j++) {
        float x = v[j] + (bias ? bias[col0 + j] : 0.f);
        if (RELU) x = fmaxf(x, 0.f);
        if constexpr (EPI == 0) {
            Cf[ob + j] = x;
        } else {
            sh2 pp = splitf(x);
            Chi[ob + j] = pp.hi;
            Clo[ob + j] = pp.lo;
        }
    }
}

// split comb rows: r < Mvf -> vf[map? map[r]:r]; else te[r - Mvf]
__global__ __launch_bounds__(256) void split_comb(
    const float* __restrict__ vf, const float* __restrict__ te,
    const int* __restrict__ map, int Mvf,
    short* __restrict__ dhi, short* __restrict__ dlo)
{
    const int r = blockIdx.x;
    const float* srow;
    if (r < Mvf) srow = vf + (long)(map ? map[r] : r) * 4096;
    else         srow = te + (long)(r - Mvf) * 4096;
    const float4* s = (const float4*)srow;
    const long db = (long)r * 4096;
    for (int i = threadIdx.x; i < 1024; i += 256) {
        float4 f = s[i];
        s16x4 h, l;
        sh2 p;
        p = splitf(f.x); h[0] = p.hi; l[0] = p.lo;
        p = splitf(f.y); h[1] = p.hi; l[1] = p.lo;
        p = splitf(f.z); h[2] = p.hi; l[2] = p.lo;
        p = splitf(f.w); h[3] = p.hi; l[3] = p.lo;
        *(s16x4*)&dhi[db + i * 4] = h;
        *(s16x4*)&dlo[db + i * 4] = l;
    }
}

// row softmax (jax.nn.softmax) -> split probs
__global__ __launch_bounds__(256) void softmax_split(
    const float* __restrict__ x, short* __restrict__ phi, short* __restrict__ plo,
    int cols)
{
    const long rb = (long)blockIdx.x * cols;
    const float4* xr = (const float4*)(x + rb);
    const int t = threadIdx.x;
    const int n4 = cols >> 2;
    __shared__ float red[256];
    float mx = -INFINITY;
    for (int i = t; i < n4; i += 256) {
        float4 f = xr[i];
        mx = fmaxf(fmaxf(mx, fmaxf(f.x, f.y)), fmaxf(f.z, f.w));
    }
    red[t] = mx; __syncthreads();
    for (int off = 128; off; off >>= 1) { if (t < off) red[t] = fmaxf(red[t], red[t + off]); __syncthreads(); }
    mx = red[0]; __syncthreads();
    float4 ebuf[2];
    float s = 0.f;
    int nb = 0;
    for (int i = t; i < n4; i += 256) {
        float4 f = xr[i];
        f.x = expf(f.x - mx); f.y = expf(f.y - mx); f.z = expf(f.z - mx); f.w = expf(f.w - mx);
        ebuf[nb++] = f;
        s += f.x + f.y + f.z + f.w;
    }
    red[t] = s; __syncthreads();
    for (int off = 128; off; off >>= 1) { if (t < off) red[t] += red[t + off]; __syncthreads(); }
    s = red[0];
    nb = 0;
    for (int i = t; i < n4; i += 256) {
        float4 f = ebuf[nb++];
        f.x /= s; f.y /= s; f.z /= s; f.w /= s;
        s16x4 h, l;
        sh2 p;
        p = splitf(f.x); h[0] = p.hi; l[0] = p.lo;
        p = splitf(f.y); h[1] = p.hi; l[1] = p.lo;
        p = splitf(f.z); h[2] = p.hi; l[2] = p.lo;
        p = splitf(f.w); h[3] = p.hi; l[3] = p.lo;
        *(s16x4*)&phi[rb + i * 4] = h;
        *(s16x4*)&plo[rb + i * 4] = l;
    }
}

// logits[r] = H[r,:2048] . w2 + b2
__global__ __launch_bounds__(256) void gemv_kernel(
    const float* __restrict__ H, const float* __restrict__ w2,
    const float* __restrict__ b2, float* __restrict__ logits)
{
    const int r = blockIdx.x, t = threadIdx.x;
    const float* row = H + (long)r * 2048;
    float s = 0.f;
    for (int c = t; c < 2048; c += 256) s += row[c] * w2[c];
    __shared__ float red[256];
    red[t] = s; __syncthreads();
    for (int off = 128; off; off >>= 1) { if (t < off) red[t] += red[t + off]; __syncthreads(); }
    if (!t) logits[r] = red[0] + b2[0];
}

// exact lax.top_k: bitonic full sort, desc by val, ties idx asc. blockDim==n.
__global__ void topk_kernel(const float* __restrict__ vals, int n, int k, int* __restrict__ out)
{
    __shared__ float sv[1024];
    __shared__ int   si[1024];
    const int t = threadIdx.x;
    sv[t] = vals[t]; si[t] = t;
    for (int size = 2; size <= n; size <<= 1) {
        for (int stride = size >> 1; stride > 0; stride >>= 1) {
            __syncthreads();
            const int j = t ^ stride;
            if (j > t) {
                float av = sv[t], bv = sv[j];
                int ai = si[t], bi = si[j];
                const bool before = (av > bv) || (av == bv && ai < bi);
                const bool dir = ((t & size) == 0);
                if (dir ? !before : before) { sv[t] = bv; si[t] = bi; sv[j] = av; si[j] = ai; }
            }
        }
    }
    __syncthreads();
    if (t < k) out[t] = si[t];
}

// fused: selidx[i] = idx1[idx2[i]]; remidx = ascending complement of selidx
__global__ void sel_complement_kernel(const int* __restrict__ idx1,
                                      const int* __restrict__ idx2,
                                      int* __restrict__ selidx,
                                      int* __restrict__ remidx)
{
    __shared__ int mask[1024];
    __shared__ int scan[1024];
    const int t = threadIdx.x;
    mask[t] = 0;
    __syncthreads();
    if (t < 256) {
        const int s = idx1[idx2[t]];
        selidx[t] = s;
        mask[s] = 1;
    }
    __syncthreads();
    const int keep = 1 - mask[t];
    scan[t] = keep;
    __syncthreads();
    for (int off = 1; off < 1024; off <<= 1) {
        int v = scan[t];
        if (t >= off) v += scan[t - off];
        __syncthreads();
        scan[t] = v;
        __syncthreads();
    }
    if (keep) remidx[scan[t] - 1] = t;
}

// fused merge prep: gather fp32 row + split hi/lo + row L2 norm.
__global__ __launch_bounds__(256) void prep_merge(
    const float* __restrict__ vf,
    const int* __restrict__ remidx, const int* __restrict__ selidx,
    float* __restrict__ rem_f, float* __restrict__ sel_f,
    short* __restrict__ remhi, short* __restrict__ remlo,
    short* __restrict__ selhi, short* __restrict__ sello,
    float* __restrict__ nr, float* __restrict__ ns)
{
    const int b = blockIdx.x, t = threadIdx.x;
    const bool isrem = (b < 768);
    const int r = isrem ? b : b - 768;
    const int sr = isrem ? remidx[r] : selidx[r];
    const float4* s = (const float4*)(vf + (long)sr * 4096);
    float* dstF = (isrem ? rem_f : sel_f) + (long)r * 4096;
    short* dhi = (isrem ? remhi : selhi) + (long)r * 4096;
    short* dlo = (isrem ? remlo : sello) + (long)r * 4096;
    for (int i = t; i < 1024; i += 256) {
        float4 f = s[i];
        *(float4*)&dstF[i * 4] = f;
        s16x4 h, l;
        sh2 p;
        p = splitf(f.x); h[0] = p.hi; l[0] = p.lo;
        p = splitf(f.y); h[1] = p.hi; l[1] = p.lo;
        p = splitf(f.z); h[2] = p.hi; l[2] = p.lo;
        p = splitf(f.w); h[3] = p.hi; l[3] = p.lo;
        *(s16x4*)&dhi[i * 4] = h;
        *(s16x4*)&dlo[i * 4] = l;
    }
    __syncthreads();
    float ss = 0.f;
    for (int c = t; c < 4096; c += 256) { float v = dstF[c]; ss += v * v; }
    __shared__ float red[256];
    red[t] = ss; __syncthreads();
    for (int off = 128; off; off >>= 1) { if (t < off) red[t] += red[t + off]; __syncthreads(); }
    if (!t) (isrem ? nr : ns)[r] = sqrtf(red[0]);
}

__global__ __launch_bounds__(256) void argmax_kernel(
    const float* __restrict__ S, const float* __restrict__ nr,
    const float* __restrict__ ns, int* __restrict__ best)
{
    const int r = blockIdx.x, t = threadIdx.x;
    float v = S[(long)r * 256 + t] / fmaxf(nr[r] * ns[t], 1e-8f);
    __shared__ float bv[256];
    __shared__ int bi[256];
    bv[t] = v; bi[t] = t; __syncthreads();
    for (int off = 128; off; off >>= 1) {
        if (t < off) {
            float ov = bv[t + off]; int oi = bi[t + off];
            if (ov > bv[t] || (ov == bv[t] && oi < bi[t])) { bv[t] = ov; bi[t] = oi; }
        }
        __syncthreads();
    }
    if (!t) best[r] = bi[0];
}

__global__ __launch_bounds__(256) void merge_kernel(
    const float* __restrict__ selb, const float* __restrict__ rem,
    const int* __restrict__ best, const float* __restrict__ nr,
    const float* __restrict__ ns, float* __restrict__ out)
{
    const int j = blockIdx.x, t = threadIdx.x;
    __shared__ int sbest[768];
    __shared__ float snr[768];
    __shared__ float red[256];
    for (int i = t; i < 768; i += 256) { sbest[i] = best[i]; snr[i] = nr[i]; }
    __syncthreads();
    float acc[16];
#pragma unroll
    for (int d = 0; d < 16; d++) acc[d] = 0.f;
    int cnt = 0; float smax = 0.f;
    const int base = t * 16;
    for (int i = 0; i < 768; i++) {
        if (sbest[i] == j) {
            cnt++;
            smax = fmaxf(smax, snr[i]);
            const float* rp = rem + (long)i * 4096 + base;
#pragma unroll
            for (int d = 0; d < 16; d += 4) {
                float4 x4 = *(const float4*)(rp + d);
                acc[d] += x4.x; acc[d + 1] += x4.y; acc[d + 2] += x4.z; acc[d + 3] += x4.w;
            }
        }
    }
    const float* sp = selb + (long)j * 4096 + base;
    float mean[16]; float ss = 0.f;
    const float denom = (float)(cnt + 1);
#pragma unroll
    for (int d = 0; d < 16; d++) { mean[d] = (sp[d] + acc[d]) / denom; ss += mean[d] * mean[d]; }
    red[t] = ss; __syncthreads();
    for (int off = 128; off; off >>= 1) { if (t < off) red[t] += red[t + off]; __syncthreads(); }
    const float nm = sqrtf(red[0]);
    const float mx = fmaxf(ns[j], cnt > 0 ? smax : 0.f);
    float* op = out + (long)j * 4096 + base;
#pragma unroll
    for (int d = 0; d < 16; d++) op[d] = (cnt > 0) ? (mean[d] / nm) * mx : sp[d];
}

// ============================================================================
// host orchestration
// ============================================================================
extern "C" void kernel_launch(void* const* d_in, const int* in_sizes, int n_in,
                              void* d_out, int out_size, void* d_ws, size_t ws_size,
                              hipStream_t stream)
{
    const float* vf   = (const float*)d_in[0];   // 1024 x 4096
    const float* te   = (const float*)d_in[1];   // 128 x 4096
    const float* inw  = (const float*)d_in[3];   // 4 x 12288 x 4096
    const float* inb  = (const float*)d_in[4];   // 4 x 12288
    const float* outw = (const float*)d_in[5];   // 4 x 4096 x 4096
    const float* outb = (const float*)d_in[6];   // 4 x 4096
    const float* w1   = (const float*)d_in[7];   // 2 x 2048 x 4096
    const float* b1   = (const float*)d_in[8];   // 2 x 2048
    const float* w2   = (const float*)d_in[9];   // 2 x 2048
    const float* b2   = (const float*)d_in[10];  // 2
    float* out = (float*)d_out;                  // 256 x 4096
    char* base = (char*)d_ws;

    char* qkR = base;                 // 37,748,736 : qk split / probs / partials
    char* vTR = base + 37748736;      // 18,874,368 : vT split
    char* scR = vTR + 18874368;       // 37,748,736 : comb/scor/o/g/hbuf/final
    float* smalls = (float*)(scR + 37748736);
    // large split-K partial scratch (ws ~3 GiB per poison WRITE_SIZE)
    float* pbig = (float*)(base + 134217728);    // 128 MB offset, <=67 MB used

    short* qkhi = (short*)qkR;
    short* qklo = (short*)(qkR + 18874368);
    short* vThi = (short*)vTR;
    short* vTlo = (short*)(vTR + 9437184);
    float* hbuf = (float*)scR;

    float* logits = smalls;
    float* nr     = smalls + 1024;
    float* ns     = smalls + 1792;
    int* idx1   = (int*)(smalls + 2048);
    int* idx2   = (int*)(smalls + 2560);
    int* selidx = (int*)(smalls + 2816);
    int* remidx = (int*)(smalls + 3072);
    int* best   = (int*)(smalls + 3840);

    const float scl = (float)(1.0 / sqrt(512.0));
    const int NOSKIP = 1 << 30;

    for (int m = 0; m < 2; m++) {
        const int Mq  = m ? 512 : 1024;
        const int Mkv = m ? 640 : 1152;
        const float* Wqkv = inw + (size_t)(2 * m) * 12288 * 4096;
        const float* bqkv = inb + (size_t)(2 * m) * 12288;
        const float* ow = outw + (size_t)(2 * m) * 4096 * 4096;
        const float* ob = outb + (size_t)(2 * m) * 4096;

        // ---- comb split (fused vf+te) ----
        short* chi = (short*)scR;
        short* clo = (short*)(scR + (size_t)Mkv * 4096 * 2);
        split_comb<<<Mkv, 256, 0, stream>>>(vf, te, m ? idx1 : nullptr, Mq, chi, clo);
        // ---- fused in-proj: q,k -> qk split; v -> vT split (transposed) ----
        if (m == 0) {
            mfma_gemm256<<<dim3(48, 5, 1), 512, 0, stream>>>(
                chi, clo, 4096, Wqkv, 4096, qkhi, qklo, vThi, vTlo,
                8192, 1152, 4096, 1152, bqkv, 1024);
        } else {
            mfma_gemm<0, 2, false><<<dim3(96, Mkv / 128, 1), 256, 0, stream>>>(
                chi, clo, 4096, 0, Wqkv, nullptr, nullptr, 4096, 0,
                nullptr, qkhi, qklo, vThi, vTlo, 8192, 1152, 0, 4096, 1, 1.f,
                bqkv, 512);
        }
        // ---- scores[h] = scl * q_h @ k_h^T (fp32) ----
        float* scor = (float*)(m ? (scR + 10485760) : scR);
        mfma_gemm<1, 0, false><<<dim3(Mkv / 128, Mq / 128, 8), 256, 0, stream>>>(
            qkhi, qklo, 8192, 512, nullptr, qkhi + 4096, qklo + 4096, 8192, 512,
            scor, nullptr, nullptr, nullptr, nullptr, Mkv, 0, (long)Mq * Mkv,
            512, 1, scl, nullptr, NOSKIP);
        // ---- softmax -> split probs ----
        short* phi = (short*)qkR;
        short* plo = (short*)(qkR + (size_t)8 * Mq * Mkv * 2);
        softmax_split<<<8 * Mq, 256, 0, stream>>>(scor, phi, plo, Mkv);
        // ---- PV: o = probs @ vT^T -> obuf split ----
        short* ohi = (short*)scR;
        short* olo = (short*)(scR + (size_t)Mq * 4096 * 2);
        if (m == 0) {
            mfma_gemm<1, 1, false><<<dim3(4, 8, 8), 256, 0, stream>>>(
                phi, plo, Mkv, (long)Mq * Mkv, nullptr, vThi, vTlo, 1152, 512L * 1152,
                nullptr, ohi, olo, nullptr, nullptr, 4096, 0, 512, Mkv, 1, 1.f,
                nullptr, NOSKIP);
        } else {
            float* Ppv = (float*)(qkR + 20971520);
            mfma_gemm<1, 0, false><<<dim3(4, 4, 16), 256, 0, stream>>>(
                phi, plo, Mkv, (long)Mq * Mkv, nullptr, vThi, vTlo, 1152, 512L * 1152,
                Ppv, nullptr, nullptr, nullptr, nullptr, 512, 0, 262144,
                Mkv, 2, 1.f, nullptr, NOSKIP);
            reduce_k<1, false><<<dim3(256, 8), 256, 0, stream>>>(
                Ppv, 262144, 2, 262144, 512, 4096, 512, nullptr, ohi, olo, nullptr);
        }
        // ---- out-proj: g = o @ ow^T + ob (256^2 split-K -> 256 blocks) ----
        short* ghi = (short*)(scR + (size_t)Mq * 4096 * 4);
        short* glo = (short*)(scR + (size_t)Mq * 4096 * 6);
        {
            const int SKg = m ? 8 : 4;
            const long zst = (long)Mq * 4096;
            mfma_gemm256sk<<<dim3(16, Mq / 256, SKg), 512, 0, stream>>>(
                ohi, olo, 4096, ow, 4096, pbig, zst, 4096, 4096, SKg);
            reduce_k<1, false><<<dim3((int)(zst / 1024), 1), 256, 0, stream>>>(
                pbig, zst, SKg, (int)zst, 4096, 4096, 0, nullptr, ghi, glo, ob);
        }
        // ---- MLP: h = relu(g @ w1^T + b1) (256^2 split-K -> 256 blocks) ----
        {
            const int SKm = m ? 16 : 8;
            const long zst = (long)Mq * 2048;
            mfma_gemm256sk<<<dim3(8, Mq / 256, SKm), 512, 0, stream>>>(
                ghi, glo, 4096, w1 + (size_t)m * 2048 * 4096, 4096,
                pbig, zst, 2048, 4096, SKm);
            reduce_k<0, true><<<dim3((int)(zst / 1024), 1), 256, 0, stream>>>(
                pbig, zst, SKm, (int)zst, 2048, 2048, 0, hbuf, nullptr, nullptr,
                b1 + (size_t)m * 2048);
        }
        gemv_kernel<<<Mq, 256, 0, stream>>>(hbuf, w2 + (size_t)m * 2048, b2 + m, logits);
        if (m == 0) topk_kernel<<<1, 1024, 0, stream>>>(logits, 1024, 512, idx1);
        else        topk_kernel<<<1, 512, 0, stream>>>(logits, 512, 256, idx2);
    }

    // ---- merge phase ----
    short* remhi = (short*)scR;
    short* remlo = (short*)(scR + 6291456);
    short* selhi = (short*)(scR + 12582912);
    short* sello = (short*)(scR + 14680064);
    float* rem_f = (float*)(scR + 16777216);
    float* sel_f = (float*)(scR + 29360128);
    float* Smat  = (float*)(scR + 33554432);

    sel_complement_kernel<<<1, 1024, 0, stream>>>(idx1, idx2, selidx, remidx);
    prep_merge<<<1024, 256, 0, stream>>>(vf, remidx, selidx, rem_f, sel_f,
                                         remhi, remlo, selhi, sello, nr, ns);
    // S = rem @ selb^T (split-K=8)
    {
        float* Ps = (float*)qkR;
        mfma_gemm<1, 0, false><<<dim3(2, 6, 8), 256, 0, stream>>>(
            remhi, remlo, 4096, 0, nullptr, selhi, sello, 4096, 0,
            Ps, nullptr, nullptr, nullptr, nullptr, 256, 0, 196608,
            4096, 8, 1.f, nullptr, NOSKIP);
        reduce_k<0, false><<<dim3(192, 1), 256, 0, stream>>>(
            Ps, 196608, 8, 196608, 256, 256, 0, Smat, nullptr, nullptr, nullptr);
    }
    argmax_kernel<<<768, 256, 0, stream>>>(Smat, nr, ns, best);
    merge_kernel<<<256, 256, 0, stream>>>(sel_f, rem_f, best, nr, ns, out);
}